// Round 2
// baseline (4268.074 us; speedup 1.0000x reference)
//
#include <hip/hip_runtime.h>

// GCN encoder: 2× GCNConv (D_EMB=64 -> D_HID=128 -> D_EMB=64), f32.
// Self-loop messages fused into GEMM epilogue: ACC[i] = X[i] * dinv[i]^2.

constexpr int D_EMB = 64;
constexpr int D_HID = 128;

__global__ __launch_bounds__(256) void k_deg_init(int* __restrict__ deg, int N) {
    int i = blockIdx.x * 256 + threadIdx.x;
    if (i < N) deg[i] = 0;
}

__global__ __launch_bounds__(256) void k_deg_count(const int* __restrict__ dst,
                                                   int* __restrict__ deg, int E) {
    int i = blockIdx.x * 256 + threadIdx.x;
    int stride = gridDim.x * 256;
    for (; i < E; i += stride) atomicAdd(&deg[dst[i]], 1);
}

__global__ __launch_bounds__(256) void k_dinv(const int* __restrict__ deg,
                                              float* __restrict__ dinv, int N) {
    int i = blockIdx.x * 256 + threadIdx.x;
    if (i < N) dinv[i] = rsqrtf((float)(deg[i] + 1));  // +1 self-loop; always > 0
}

// X = A @ W  (A: [N,K], W: [K,OUT]);  ACC = X * dinv^2  (self-loop init).
// Block: 256 threads, BM rows. Thread computes RPT rows x 4 cols.
// LDS budget: As[BM][K+1] + Ws[K][OUT] must stay < 64 KiB.
template <int K, int OUT, int BM>
__global__ __launch_bounds__(256) void k_gemm_scale(
    const float* __restrict__ A, const float* __restrict__ W,
    const float* __restrict__ dinv, float* __restrict__ X,
    float* __restrict__ ACC, int N) {
    constexpr int NCG = OUT / 4;    // col groups (float4)
    constexpr int NRG = 256 / NCG;  // row groups
    constexpr int RPT = BM / NRG;   // rows per thread

    __shared__ float As[BM][K + 1];   // +1 pad: breaks bank aliasing on column reads
    __shared__ float Ws[K][OUT];

    const int tid  = threadIdx.x;
    const int row0 = blockIdx.x * BM;

    // Stage W (K*OUT floats) via float4.
    for (int i = tid; i < K * OUT / 4; i += 256)
        ((float4*)Ws)[i] = ((const float4*)W)[i];

    // Stage A tile; scalar LDS writes (padded rows), coalesced float4 global reads.
    for (int i = tid; i < BM * K / 4; i += 256) {
        int r  = i / (K / 4);
        int k4 = i % (K / 4);
        int row = row0 + r;
        float4 v = make_float4(0.f, 0.f, 0.f, 0.f);
        if (row < N) v = ((const float4*)(A + (size_t)row * K))[k4];
        As[r][k4 * 4 + 0] = v.x;
        As[r][k4 * 4 + 1] = v.y;
        As[r][k4 * 4 + 2] = v.z;
        As[r][k4 * 4 + 3] = v.w;
    }
    __syncthreads();

    const int tc = tid % NCG;
    const int tr = tid / NCG;
    const int r0 = tr * RPT;

    float acc[RPT][4];
#pragma unroll
    for (int i = 0; i < RPT; ++i)
        acc[i][0] = acc[i][1] = acc[i][2] = acc[i][3] = 0.f;

#pragma unroll 8
    for (int k = 0; k < K; ++k) {
        float4 w = *(const float4*)&Ws[k][tc * 4];
#pragma unroll
        for (int i = 0; i < RPT; ++i) {
            float a = As[r0 + i][k];   // broadcast within row-group
            acc[i][0] = fmaf(a, w.x, acc[i][0]);
            acc[i][1] = fmaf(a, w.y, acc[i][1]);
            acc[i][2] = fmaf(a, w.z, acc[i][2]);
            acc[i][3] = fmaf(a, w.w, acc[i][3]);
        }
    }

#pragma unroll
    for (int i = 0; i < RPT; ++i) {
        int row = row0 + r0 + i;
        if (row >= N) break;           // rows contiguous per thread
        float di = dinv[row];
        float s  = di * di;
        float4 xv = make_float4(acc[i][0], acc[i][1], acc[i][2], acc[i][3]);
        ((float4*)(X + (size_t)row * OUT))[tc] = xv;
        float4 av = make_float4(xv.x * s, xv.y * s, xv.z * s, xv.w * s);
        ((float4*)(ACC + (size_t)row * OUT))[tc] = av;
    }
}

// Edge scatter, 128 dims: 32 lanes/edge, float4 gather + 4 f32 atomics per lane.
__global__ __launch_bounds__(256) void k_scatter128(
    const int* __restrict__ ei, const float* __restrict__ dinv,
    const float* __restrict__ X, float* __restrict__ ACC, int E) {
    int gid  = blockIdx.x * 256 + threadIdx.x;
    int e    = gid >> 5;
    int lane = gid & 31;
    if (e >= E) return;
    int   src  = ei[e];
    int   dst  = ei[E + e];
    float norm = dinv[src] * dinv[dst];
    float4 v   = ((const float4*)(X + (size_t)src * D_HID))[lane];
    float* out = ACC + (size_t)dst * D_HID + lane * 4;
    unsafeAtomicAdd(out + 0, v.x * norm);
    unsafeAtomicAdd(out + 1, v.y * norm);
    unsafeAtomicAdd(out + 2, v.z * norm);
    unsafeAtomicAdd(out + 3, v.w * norm);
}

// Edge scatter, 64 dims: 16 lanes/edge.
__global__ __launch_bounds__(256) void k_scatter64(
    const int* __restrict__ ei, const float* __restrict__ dinv,
    const float* __restrict__ X, float* __restrict__ ACC, int E) {
    int gid  = blockIdx.x * 256 + threadIdx.x;
    int e    = gid >> 4;
    int lane = gid & 15;
    if (e >= E) return;
    int   src  = ei[e];
    int   dst  = ei[E + e];
    float norm = dinv[src] * dinv[dst];
    float4 v   = ((const float4*)(X + (size_t)src * D_EMB))[lane];
    float* out = ACC + (size_t)dst * D_EMB + lane * 4;
    unsafeAtomicAdd(out + 0, v.x * norm);
    unsafeAtomicAdd(out + 1, v.y * norm);
    unsafeAtomicAdd(out + 2, v.z * norm);
    unsafeAtomicAdd(out + 3, v.w * norm);
}

// acc += bias (per column), optional ReLU. total4 = N*OUT/4.
template <int OUT, bool RELU>
__global__ __launch_bounds__(256) void k_bias_act(float* __restrict__ acc,
                                                  const float* __restrict__ bias,
                                                  int total4) {
    int i = blockIdx.x * 256 + threadIdx.x;
    int stride = gridDim.x * 256;
    for (; i < total4; i += stride) {
        float4 v  = ((float4*)acc)[i];
        float4 bb = ((const float4*)bias)[i % (OUT / 4)];
        v.x += bb.x; v.y += bb.y; v.z += bb.z; v.w += bb.w;
        if (RELU) {
            v.x = fmaxf(v.x, 0.f); v.y = fmaxf(v.y, 0.f);
            v.z = fmaxf(v.z, 0.f); v.w = fmaxf(v.w, 0.f);
        }
        ((float4*)acc)[i] = v;
    }
}

extern "C" void kernel_launch(void* const* d_in, const int* in_sizes, int n_in,
                              void* d_out, int out_size, void* d_ws, size_t ws_size,
                              hipStream_t stream) {
    const float* emb = (const float*)d_in[0];
    const float* W1  = (const float*)d_in[1];
    const float* b1  = (const float*)d_in[2];
    const float* W2  = (const float*)d_in[3];
    const float* b2  = (const float*)d_in[4];
    const int*   ei  = (const int*)d_in[5];

    const int N = in_sizes[0] / D_EMB;
    const int E = in_sizes[5] / 2;

    // Workspace layout (floats): x1[N*128] | acc1[N*128] | deg[N] | dinv[N]
    float* x1   = (float*)d_ws;
    float* acc1 = x1 + (size_t)N * D_HID;
    int*   deg  = (int*)(acc1 + (size_t)N * D_HID);
    float* dinv = (float*)(deg + N);
    float* x2   = x1;  // x1 dead after scatter1 -> reuse for x2
    float* out  = (float*)d_out;

    const int nb = (N + 255) / 256;

    k_deg_init<<<nb, 256, 0, stream>>>(deg, N);
    k_deg_count<<<2048, 256, 0, stream>>>(ei + E, deg, E);
    k_dinv<<<nb, 256, 0, stream>>>(deg, dinv, N);

    // Layer 1: LDS = As[64][65] + Ws[64][128] = 48.7 KiB
    k_gemm_scale<D_EMB, D_HID, 64><<<(N + 63) / 64, 256, 0, stream>>>(emb, W1, dinv, x1, acc1, N);
    k_scatter128<<<(E + 7) / 8, 256, 0, stream>>>(ei, dinv, x1, acc1, E);
    k_bias_act<D_HID, true><<<2048, 256, 0, stream>>>(acc1, b1, N * (D_HID / 4));

    // Layer 2: BM=32 keeps LDS = As[32][129] + Ws[128][64] = 48.5 KiB (<64 KiB)
    k_gemm_scale<D_HID, D_EMB, 32><<<(N + 31) / 32, 256, 0, stream>>>(acc1, W2, dinv, x2, out, N);
    k_scatter64<<<(E + 15) / 16, 256, 0, stream>>>(ei, dinv, x2, out, E);
    k_bias_act<D_EMB, false><<<2048, 256, 0, stream>>>(out, b2, N * (D_EMB / 4));
}

// Round 3
// 568.867 us; speedup vs baseline: 7.5028x; 7.5028x over previous
//
#include <hip/hip_runtime.h>

// GCN encoder, f32: 2x GCNConv (64 -> 128 -> 64).
// Strategy: transform (GEMM) -> CSR-by-dst gather-aggregate (no atomics on features).
// CSR built per call: degree count -> 3-kernel exclusive scan -> atomic slot fill.
// Gather fuses self-loop, symmetric norm, bias, ReLU.

constexpr int D_EMB = 64;
constexpr int D_HID = 128;
constexpr int SCAN_CHUNK = 1024;   // 256 threads x 4 elems

__global__ __launch_bounds__(256) void k_deg_init(int* __restrict__ deg, int N) {
    int i = blockIdx.x * 256 + threadIdx.x;
    if (i < N) deg[i] = 0;
}

__global__ __launch_bounds__(256) void k_deg_count(const int* __restrict__ dst,
                                                   int* __restrict__ deg, int E) {
    int i = blockIdx.x * 256 + threadIdx.x;
    int stride = gridDim.x * 256;
    for (; i < E; i += stride) atomicAdd(&deg[dst[i]], 1);
}

__global__ __launch_bounds__(256) void k_dinv(const int* __restrict__ deg,
                                              float* __restrict__ dinv, int N) {
    int i = blockIdx.x * 256 + threadIdx.x;
    if (i < N) dinv[i] = rsqrtf((float)(deg[i] + 1));  // +1 self-loop
}

// --- exclusive scan of deg[N] into row_ptr[N] (+ partials) ---
__global__ __launch_bounds__(256) void k_scan1(const int* __restrict__ deg,
                                               int* __restrict__ row_ptr,
                                               int* __restrict__ partial, int N) {
    __shared__ int ts[256];
    const int tid  = threadIdx.x;
    const int base = blockIdx.x * SCAN_CHUNK + tid * 4;
    int v[4], s = 0;
#pragma unroll
    for (int i = 0; i < 4; ++i) {
        int idx = base + i;
        v[i] = (idx < N) ? deg[idx] : 0;
        s += v[i];
    }
    ts[tid] = s;
    __syncthreads();
    for (int off = 1; off < 256; off <<= 1) {
        int t = (tid >= off) ? ts[tid - off] : 0;
        __syncthreads();
        ts[tid] += t;
        __syncthreads();
    }
    int run = ts[tid] - s;  // exclusive prefix of this thread within block
#pragma unroll
    for (int i = 0; i < 4; ++i) {
        int idx = base + i;
        if (idx < N) row_ptr[idx] = run;
        run += v[i];
    }
    if (tid == 255) partial[blockIdx.x] = ts[255];
}

// scan partials (nb <= 256) in one block; writes exclusive partials in place
// and row_ptr[N] = grand total.
__global__ __launch_bounds__(256) void k_scan2(int* __restrict__ partial,
                                               int* __restrict__ row_ptr,
                                               int nb, int N) {
    __shared__ int ts[256];
    const int tid = threadIdx.x;
    int s = (tid < nb) ? partial[tid] : 0;
    ts[tid] = s;
    __syncthreads();
    for (int off = 1; off < 256; off <<= 1) {
        int t = (tid >= off) ? ts[tid - off] : 0;
        __syncthreads();
        ts[tid] += t;
        __syncthreads();
    }
    if (tid < nb) partial[tid] = ts[tid] - s;  // exclusive
    if (tid == nb - 1) row_ptr[N] = ts[tid];   // total = E
}

// add block offsets; also seed cursor[] for the fill pass.
__global__ __launch_bounds__(256) void k_scan3(int* __restrict__ row_ptr,
                                               const int* __restrict__ partial,
                                               int* __restrict__ cursor, int N) {
    const int base = blockIdx.x * SCAN_CHUNK + threadIdx.x * 4;
    const int off  = partial[blockIdx.x];
#pragma unroll
    for (int i = 0; i < 4; ++i) {
        int idx = base + i;
        if (idx < N) {
            int rp = row_ptr[idx] + off;
            row_ptr[idx] = rp;
            cursor[idx]  = rp;
        }
    }
}

// pair[pos] = {bitcast(src), dinv[src]} grouped by dst.
__global__ __launch_bounds__(256) void k_fill(const int* __restrict__ ei,
                                              const float* __restrict__ dinv,
                                              int* __restrict__ cursor,
                                              float2* __restrict__ pair, int E) {
    int e = blockIdx.x * 256 + threadIdx.x;
    if (e >= E) return;
    int s = ei[e];
    int d = ei[E + e];
    int pos = atomicAdd(&cursor[d], 1);
    pair[pos] = make_float2(__int_as_float(s), dinv[s]);
}

// X = A @ W  (A: [N,K], W: [K,OUT]). 256 threads, BM rows/block.
template <int K, int OUT, int BM>
__global__ __launch_bounds__(256) void k_gemm(
    const float* __restrict__ A, const float* __restrict__ W,
    float* __restrict__ X, int N) {
    constexpr int NCG = OUT / 4;
    constexpr int NRG = 256 / NCG;
    constexpr int RPT = BM / NRG;

    __shared__ float As[BM][K + 1];
    __shared__ float Ws[K][OUT];

    const int tid  = threadIdx.x;
    const int row0 = blockIdx.x * BM;

    for (int i = tid; i < K * OUT / 4; i += 256)
        ((float4*)Ws)[i] = ((const float4*)W)[i];

    for (int i = tid; i < BM * K / 4; i += 256) {
        int r  = i / (K / 4);
        int k4 = i % (K / 4);
        int row = row0 + r;
        float4 v = make_float4(0.f, 0.f, 0.f, 0.f);
        if (row < N) v = ((const float4*)(A + (size_t)row * K))[k4];
        As[r][k4 * 4 + 0] = v.x;
        As[r][k4 * 4 + 1] = v.y;
        As[r][k4 * 4 + 2] = v.z;
        As[r][k4 * 4 + 3] = v.w;
    }
    __syncthreads();

    const int tc = tid % NCG;
    const int tr = tid / NCG;
    const int r0 = tr * RPT;

    float acc[RPT][4];
#pragma unroll
    for (int i = 0; i < RPT; ++i)
        acc[i][0] = acc[i][1] = acc[i][2] = acc[i][3] = 0.f;

#pragma unroll 8
    for (int k = 0; k < K; ++k) {
        float4 w = *(const float4*)&Ws[k][tc * 4];
#pragma unroll
        for (int i = 0; i < RPT; ++i) {
            float a = As[r0 + i][k];
            acc[i][0] = fmaf(a, w.x, acc[i][0]);
            acc[i][1] = fmaf(a, w.y, acc[i][1]);
            acc[i][2] = fmaf(a, w.z, acc[i][2]);
            acc[i][3] = fmaf(a, w.w, acc[i][3]);
        }
    }

#pragma unroll
    for (int i = 0; i < RPT; ++i) {
        int row = row0 + r0 + i;
        if (row >= N) break;
        ((float4*)(X + (size_t)row * OUT))[tc] =
            make_float4(acc[i][0], acc[i][1], acc[i][2], acc[i][3]);
    }
}

// One wave per node: OUT[v] = act( X[v]*dv^2 + sum_u X[u]*dinv[u]*dv + bias ).
// D=128: lane holds float2; D=64: lane holds float.
template <int D, bool RELU>
__global__ __launch_bounds__(256) void k_gather(
    const int* __restrict__ row_ptr, const float2* __restrict__ pair,
    const float* __restrict__ dinv, const float* __restrict__ X,
    const float* __restrict__ bias, float* __restrict__ OUT, int N) {
    constexpr int PL = D / 64;  // floats per lane (1 or 2)
    const int wid  = (blockIdx.x * 256 + threadIdx.x) >> 6;
    const int lane = threadIdx.x & 63;
    if (wid >= N) return;
    const int v = wid;
    const float dv = dinv[v];
    const int beg = row_ptr[v];
    const int end = row_ptr[v + 1];

    float acc[PL];
    if (PL == 2) {
        const float2 xv = *(const float2*)(X + (size_t)v * D + lane * 2);
        acc[0] = xv.x * dv * dv;
        acc[1] = xv.y * dv * dv;
    } else {
        acc[0] = X[(size_t)v * D + lane] * dv * dv;
    }

    float2 pr = (beg < end) ? pair[beg] : make_float2(0.f, 0.f);
    for (int j = beg; j < end; ++j) {
        float2 cur = pr;
        if (j + 1 < end) pr = pair[j + 1];          // prefetch next edge rec
        const int   u = __float_as_int(cur.x);
        const float w = cur.y * dv;
        if (PL == 2) {
            const float2 xu = *(const float2*)(X + (size_t)u * D + lane * 2);
            acc[0] = fmaf(xu.x, w, acc[0]);
            acc[1] = fmaf(xu.y, w, acc[1]);
        } else {
            acc[0] = fmaf(X[(size_t)u * D + lane], w, acc[0]);
        }
    }

    if (PL == 2) {
        float r0 = acc[0] + bias[lane * 2];
        float r1 = acc[1] + bias[lane * 2 + 1];
        if (RELU) { r0 = fmaxf(r0, 0.f); r1 = fmaxf(r1, 0.f); }
        *(float2*)(OUT + (size_t)v * D + lane * 2) = make_float2(r0, r1);
    } else {
        float r0 = acc[0] + bias[lane];
        if (RELU) r0 = fmaxf(r0, 0.f);
        OUT[(size_t)v * D + lane] = r0;
    }
}

extern "C" void kernel_launch(void* const* d_in, const int* in_sizes, int n_in,
                              void* d_out, int out_size, void* d_ws, size_t ws_size,
                              hipStream_t stream) {
    const float* emb = (const float*)d_in[0];
    const float* W1  = (const float*)d_in[1];
    const float* b1  = (const float*)d_in[2];
    const float* W2  = (const float*)d_in[3];
    const float* b2  = (const float*)d_in[4];
    const int*   ei  = (const int*)d_in[5];

    const int N = in_sizes[0] / D_EMB;
    const int E = in_sizes[5] / 2;

    // Workspace (floats): x1[N*128] | h1[N*128] | pair[2E] | row_ptr[N+1] | cursor[N] | deg[N] | dinv[N] | partial[256]
    float*  x1      = (float*)d_ws;
    float*  h1      = x1 + (size_t)N * D_HID;
    float2* pair    = (float2*)(h1 + (size_t)N * D_HID);
    int*    row_ptr = (int*)(pair + E);
    int*    cursor  = row_ptr + (N + 1);
    int*    deg     = cursor + N;
    float*  dinv    = (float*)(deg + N);
    int*    partial = (int*)(dinv + N);
    float*  x2      = x1;  // x1 dead after gather1
    float*  out     = (float*)d_out;

    const int nbN   = (N + 255) / 256;
    const int nbSc  = (N + SCAN_CHUNK - 1) / SCAN_CHUNK;  // 98 for N=100k (<=256)
    const int nbE   = (E + 255) / 256;
    const int nbGat = (N * 64 + 255) / 256;  // one wave per node

    // CSR-by-dst build
    k_deg_init<<<nbN, 256, 0, stream>>>(deg, N);
    k_deg_count<<<2048, 256, 0, stream>>>(ei + E, deg, E);
    k_dinv<<<nbN, 256, 0, stream>>>(deg, dinv, N);
    k_scan1<<<nbSc, 256, 0, stream>>>(deg, row_ptr, partial, N);
    k_scan2<<<1, 256, 0, stream>>>(partial, row_ptr, nbSc, N);
    k_scan3<<<nbSc, 256, 0, stream>>>(row_ptr, partial, cursor, N);
    k_fill<<<nbE, 256, 0, stream>>>(ei, dinv, cursor, pair, E);

    // Layer 1: x1 = emb @ W1 ; h1 = relu(aggregate(x1) + b1)
    k_gemm<D_EMB, D_HID, 64><<<(N + 63) / 64, 256, 0, stream>>>(emb, W1, x1, N);
    k_gather<D_HID, true><<<nbGat, 256, 0, stream>>>(row_ptr, pair, dinv, x1, b1, h1, N);

    // Layer 2: x2 = h1 @ W2 ; out = aggregate(x2) + b2
    k_gemm<D_HID, D_EMB, 32><<<(N + 31) / 32, 256, 0, stream>>>(h1, W2, x2, N);
    k_gather<D_EMB, false><<<nbGat, 256, 0, stream>>>(row_ptr, pair, dinv, x2, b2, out, N);
}

// Round 4
// 459.226 us; speedup vs baseline: 9.2941x; 1.2388x over previous
//
#include <hip/hip_runtime.h>

// GCN encoder, f32: 2x GCNConv (64 -> 128 -> 64).
// Aggregate-first layer 1:  h1 = relu((A_hat @ emb) @ W1 + b1)
// Transform-first layer 2:  out = A_hat @ (h1 @ W2) + b2
// Both aggregations are D=64 CSR-by-dst gathers, 4 edges in flight per wave.

constexpr int D_EMB = 64;
constexpr int D_HID = 128;
constexpr int SCAN_CHUNK = 1024;   // 256 threads x 4 elems

__global__ __launch_bounds__(256) void k_deg_init(int* __restrict__ deg, int N) {
    int i = blockIdx.x * 256 + threadIdx.x;
    if (i < N) deg[i] = 0;
}

__global__ __launch_bounds__(256) void k_deg_count(const int* __restrict__ dst,
                                                   int* __restrict__ deg, int E) {
    int i = blockIdx.x * 256 + threadIdx.x;
    int stride = gridDim.x * 256;
    for (; i < E; i += stride) atomicAdd(&deg[dst[i]], 1);
}

__global__ __launch_bounds__(256) void k_dinv(const int* __restrict__ deg,
                                              float* __restrict__ dinv, int N) {
    int i = blockIdx.x * 256 + threadIdx.x;
    if (i < N) dinv[i] = rsqrtf((float)(deg[i] + 1));  // +1 self-loop
}

// --- exclusive scan of deg[N] into row_ptr[N] (+ partials) ---
__global__ __launch_bounds__(256) void k_scan1(const int* __restrict__ deg,
                                               int* __restrict__ row_ptr,
                                               int* __restrict__ partial, int N) {
    __shared__ int ts[256];
    const int tid  = threadIdx.x;
    const int base = blockIdx.x * SCAN_CHUNK + tid * 4;
    int v[4], s = 0;
#pragma unroll
    for (int i = 0; i < 4; ++i) {
        int idx = base + i;
        v[i] = (idx < N) ? deg[idx] : 0;
        s += v[i];
    }
    ts[tid] = s;
    __syncthreads();
    for (int off = 1; off < 256; off <<= 1) {
        int t = (tid >= off) ? ts[tid - off] : 0;
        __syncthreads();
        ts[tid] += t;
        __syncthreads();
    }
    int run = ts[tid] - s;
#pragma unroll
    for (int i = 0; i < 4; ++i) {
        int idx = base + i;
        if (idx < N) row_ptr[idx] = run;
        run += v[i];
    }
    if (tid == 255) partial[blockIdx.x] = ts[255];
}

__global__ __launch_bounds__(256) void k_scan2(int* __restrict__ partial,
                                               int* __restrict__ row_ptr,
                                               int nb, int N) {
    __shared__ int ts[256];
    const int tid = threadIdx.x;
    int s = (tid < nb) ? partial[tid] : 0;
    ts[tid] = s;
    __syncthreads();
    for (int off = 1; off < 256; off <<= 1) {
        int t = (tid >= off) ? ts[tid - off] : 0;
        __syncthreads();
        ts[tid] += t;
        __syncthreads();
    }
    if (tid < nb) partial[tid] = ts[tid] - s;
    if (tid == nb - 1) row_ptr[N] = ts[tid];
}

__global__ __launch_bounds__(256) void k_scan3(int* __restrict__ row_ptr,
                                               const int* __restrict__ partial,
                                               int* __restrict__ cursor, int N) {
    const int base = blockIdx.x * SCAN_CHUNK + threadIdx.x * 4;
    const int off  = partial[blockIdx.x];
#pragma unroll
    for (int i = 0; i < 4; ++i) {
        int idx = base + i;
        if (idx < N) {
            int rp = row_ptr[idx] + off;
            row_ptr[idx] = rp;
            cursor[idx]  = rp;
        }
    }
}

// pair[pos] = {bitcast(src), dinv[src]} grouped by dst.
__global__ __launch_bounds__(256) void k_fill(const int* __restrict__ ei,
                                              const float* __restrict__ dinv,
                                              int* __restrict__ cursor,
                                              float2* __restrict__ pair, int E) {
    int e = blockIdx.x * 256 + threadIdx.x;
    if (e >= E) return;
    int s = ei[e];
    int d = ei[E + e];
    int pos = atomicAdd(&cursor[d], 1);
    pair[pos] = make_float2(__int_as_float(s), dinv[s]);
}

// X = A @ W, optional +bias / ReLU epilogue. 256 threads, BM rows/block.
template <int K, int OUT, int BM, bool BIAS, bool RELU>
__global__ __launch_bounds__(256) void k_gemm(
    const float* __restrict__ A, const float* __restrict__ W,
    const float* __restrict__ bias, float* __restrict__ X, int N) {
    constexpr int NCG = OUT / 4;
    constexpr int NRG = 256 / NCG;
    constexpr int RPT = BM / NRG;

    __shared__ float As[BM][K + 1];
    __shared__ float Ws[K][OUT];

    const int tid  = threadIdx.x;
    const int row0 = blockIdx.x * BM;

    for (int i = tid; i < K * OUT / 4; i += 256)
        ((float4*)Ws)[i] = ((const float4*)W)[i];

    for (int i = tid; i < BM * K / 4; i += 256) {
        int r  = i / (K / 4);
        int k4 = i % (K / 4);
        int row = row0 + r;
        float4 v = make_float4(0.f, 0.f, 0.f, 0.f);
        if (row < N) v = ((const float4*)(A + (size_t)row * K))[k4];
        As[r][k4 * 4 + 0] = v.x;
        As[r][k4 * 4 + 1] = v.y;
        As[r][k4 * 4 + 2] = v.z;
        As[r][k4 * 4 + 3] = v.w;
    }
    __syncthreads();

    const int tc = tid % NCG;
    const int tr = tid / NCG;
    const int r0 = tr * RPT;

    float acc[RPT][4];
#pragma unroll
    for (int i = 0; i < RPT; ++i)
        acc[i][0] = acc[i][1] = acc[i][2] = acc[i][3] = 0.f;

#pragma unroll 8
    for (int k = 0; k < K; ++k) {
        float4 w = *(const float4*)&Ws[k][tc * 4];
#pragma unroll
        for (int i = 0; i < RPT; ++i) {
            float a = As[r0 + i][k];
            acc[i][0] = fmaf(a, w.x, acc[i][0]);
            acc[i][1] = fmaf(a, w.y, acc[i][1]);
            acc[i][2] = fmaf(a, w.z, acc[i][2]);
            acc[i][3] = fmaf(a, w.w, acc[i][3]);
        }
    }

    float4 bb = make_float4(0.f, 0.f, 0.f, 0.f);
    if (BIAS) bb = ((const float4*)bias)[tc];

#pragma unroll
    for (int i = 0; i < RPT; ++i) {
        int row = row0 + r0 + i;
        if (row >= N) break;
        float4 v = make_float4(acc[i][0], acc[i][1], acc[i][2], acc[i][3]);
        if (BIAS) { v.x += bb.x; v.y += bb.y; v.z += bb.z; v.w += bb.w; }
        if (RELU) {
            v.x = fmaxf(v.x, 0.f); v.y = fmaxf(v.y, 0.f);
            v.z = fmaxf(v.z, 0.f); v.w = fmaxf(v.w, 0.f);
        }
        ((float4*)(X + (size_t)row * OUT))[tc] = v;
    }
}

// D=64 gather: one wave per node, 4 quarter-waves x (16 lanes * float4).
// Quarter q processes edges beg+q, beg+q+4, ... (4 edges in flight per wave).
// OUT[v] = X[v]*dv^2 + sum_u X[u]*dinv[u]*dv  (+ bias).
template <bool BIAS>
__global__ __launch_bounds__(256) void k_gather64(
    const int* __restrict__ row_ptr, const float2* __restrict__ pair,
    const float* __restrict__ dinv, const float* __restrict__ X,
    const float* __restrict__ bias, float* __restrict__ OUT, int N) {
    const int wid  = (blockIdx.x * 256 + threadIdx.x) >> 6;
    const int lane = threadIdx.x & 63;
    const int q    = lane >> 4;    // quarter 0..3
    const int l    = lane & 15;    // lane within quarter
    if (wid >= N) return;
    const int v = wid;
    const float dv = dinv[v];
    const int beg = row_ptr[v];
    const int end = row_ptr[v + 1];

    float4 acc = make_float4(0.f, 0.f, 0.f, 0.f);

    int j = beg + q;
    float2 pr = (j < end) ? pair[j] : make_float2(0.f, 0.f);
    while (j < end) {
        float2 cur = pr;
        int jn = j + 4;
        if (jn < end) pr = pair[jn];            // prefetch next record
        const int   u = __float_as_int(cur.x);
        const float w = cur.y * dv;
        float4 xu = ((const float4*)(X + (size_t)u * 64))[l];
        acc.x = fmaf(xu.x, w, acc.x);
        acc.y = fmaf(xu.y, w, acc.y);
        acc.z = fmaf(xu.z, w, acc.z);
        acc.w = fmaf(xu.w, w, acc.w);
        j = jn;
    }

    // Sum the 4 quarter partials (same dims in each quarter): xor-reduce 16, 32.
#pragma unroll
    for (int m = 16; m <= 32; m <<= 1) {
        acc.x += __shfl_xor(acc.x, m);
        acc.y += __shfl_xor(acc.y, m);
        acc.z += __shfl_xor(acc.z, m);
        acc.w += __shfl_xor(acc.w, m);
    }

    if (q == 0) {
        float4 xv = ((const float4*)(X + (size_t)v * 64))[l];
        float s = dv * dv;
        acc.x = fmaf(xv.x, s, acc.x);
        acc.y = fmaf(xv.y, s, acc.y);
        acc.z = fmaf(xv.z, s, acc.z);
        acc.w = fmaf(xv.w, s, acc.w);
        if (BIAS) {
            float4 bb = ((const float4*)bias)[l];
            acc.x += bb.x; acc.y += bb.y; acc.z += bb.z; acc.w += bb.w;
        }
        ((float4*)(OUT + (size_t)v * 64))[l] = acc;
    }
}

extern "C" void kernel_launch(void* const* d_in, const int* in_sizes, int n_in,
                              void* d_out, int out_size, void* d_ws, size_t ws_size,
                              hipStream_t stream) {
    const float* emb = (const float*)d_in[0];
    const float* W1  = (const float*)d_in[1];
    const float* b1  = (const float*)d_in[2];
    const float* W2  = (const float*)d_in[3];
    const float* b2  = (const float*)d_in[4];
    const int*   ei  = (const int*)d_in[5];

    const int N = in_sizes[0] / D_EMB;
    const int E = in_sizes[5] / 2;

    // Workspace (floats): a1[N*64] | h1[N*128] | pair[2E] | row_ptr[N+1] | cursor[N] | deg[N] | dinv[N] | partial[256]
    float*  a1      = (float*)d_ws;
    float*  h1      = a1 + (size_t)N * D_EMB;
    float2* pair    = (float2*)(h1 + (size_t)N * D_HID);
    int*    row_ptr = (int*)(pair + E);
    int*    cursor  = row_ptr + (N + 1);
    int*    deg     = cursor + N;
    float*  dinv    = (float*)(deg + N);
    int*    partial = (int*)(dinv + N);
    float*  x2      = a1;  // a1 dead after gemm1 -> reuse for x2
    float*  out     = (float*)d_out;

    const int nbN   = (N + 255) / 256;
    const int nbSc  = (N + SCAN_CHUNK - 1) / SCAN_CHUNK;  // 98 (<=256)
    const int nbE   = (E + 255) / 256;
    const int nbGat = (N * 64 + 255) / 256;  // one wave per node

    // CSR-by-dst build
    k_deg_init<<<nbN, 256, 0, stream>>>(deg, N);
    k_deg_count<<<2048, 256, 0, stream>>>(ei + E, deg, E);
    k_dinv<<<nbN, 256, 0, stream>>>(deg, dinv, N);
    k_scan1<<<nbSc, 256, 0, stream>>>(deg, row_ptr, partial, N);
    k_scan2<<<1, 256, 0, stream>>>(partial, row_ptr, nbSc, N);
    k_scan3<<<nbSc, 256, 0, stream>>>(row_ptr, partial, cursor, N);
    k_fill<<<nbE, 256, 0, stream>>>(ei, dinv, cursor, pair, E);

    // Layer 1: a1 = A_hat @ emb ; h1 = relu(a1 @ W1 + b1)
    k_gather64<false><<<nbGat, 256, 0, stream>>>(row_ptr, pair, dinv, emb, nullptr, a1, N);
    k_gemm<D_EMB, D_HID, 64, true, true><<<(N + 63) / 64, 256, 0, stream>>>(a1, W1, b1, h1, N);

    // Layer 2: x2 = h1 @ W2 ; out = A_hat @ x2 + b2
    k_gemm<D_HID, D_EMB, 32, false, false><<<(N + 31) / 32, 256, 0, stream>>>(h1, W2, nullptr, x2, N);
    k_gather64<true><<<nbGat, 256, 0, stream>>>(row_ptr, pair, dinv, x2, b2, out, N);
}